// Round 1
// baseline (6731.312 us; speedup 1.0000x reference)
//
#include <hip/hip_runtime.h>

// GINNet on MI355X.
// Pipeline:
//   k_features : x[i] = [pos | emb[z]]  -> ws.x  and ws.acc (acc pre-seeded with x)
//   k_init_out : out[g] = fcb[0]
//   k_scatter  : acc[dst] += x[src]  (16M edges, fp32 HW atomics)
//   k_mlp_pool : per node: s = relu(relu((x+agg)@W1+b1)@W2+b2) . fcW ;
//                segmented block reduce over sorted batch -> atomicAdd(out[g], s)
// Note: pooled@fcW+fcb == sum_i (h_i . fcW) + fcb  (linearity) -> no pooled matrix.

#define N_NODES  1000000
#define N_EDGES  16000000
#define N_GRAPHS 10000

__global__ __launch_bounds__(256) void k_features(
    const float* __restrict__ pos, const int* __restrict__ z,
    const float* __restrict__ emb, float* __restrict__ x, float* __restrict__ acc)
{
    int i = blockIdx.x * 256 + threadIdx.x;
    if (i >= N_NODES) return;
    float p0 = pos[i * 3 + 0], p1 = pos[i * 3 + 1], p2 = pos[i * 3 + 2];
    int zi = z[i];
    const float* e = emb + zi * 5;
    float4 a = make_float4(p0, p1, p2, e[0]);
    float4 b = make_float4(e[1], e[2], e[3], e[4]);
    float4* xv = (float4*)x;
    float4* av = (float4*)acc;
    xv[(size_t)i * 2 + 0] = a;
    xv[(size_t)i * 2 + 1] = b;
    av[(size_t)i * 2 + 0] = a;
    av[(size_t)i * 2 + 1] = b;
}

__global__ __launch_bounds__(256) void k_init_out(
    const float* __restrict__ fcb, float* __restrict__ out)
{
    int i = blockIdx.x * 256 + threadIdx.x;
    if (i < N_GRAPHS) out[i] = fcb[0];
}

__global__ __launch_bounds__(256) void k_scatter(
    const int* __restrict__ ei, const float* __restrict__ x, float* __restrict__ acc)
{
    int e = blockIdx.x * 256 + threadIdx.x;
    if (e >= N_EDGES) return;
    int s = ei[e];
    int d = ei[N_EDGES + e];
    const float4* xv = (const float4*)x;
    float4 a = xv[(size_t)s * 2 + 0];
    float4 b = xv[(size_t)s * 2 + 1];
    float* p = acc + (size_t)d * 8;
    unsafeAtomicAdd(p + 0, a.x);
    unsafeAtomicAdd(p + 1, a.y);
    unsafeAtomicAdd(p + 2, a.z);
    unsafeAtomicAdd(p + 3, a.w);
    unsafeAtomicAdd(p + 4, b.x);
    unsafeAtomicAdd(p + 5, b.y);
    unsafeAtomicAdd(p + 6, b.z);
    unsafeAtomicAdd(p + 7, b.w);
}

__global__ __launch_bounds__(256) void k_mlp_pool(
    const float* __restrict__ acc, const int* __restrict__ batch,
    const float* __restrict__ W1, const float* __restrict__ b1,
    const float* __restrict__ W2, const float* __restrict__ b2,
    const float* __restrict__ fcW, float* __restrict__ out)
{
    __shared__ float sW1[512];    // [8][64]
    __shared__ float sW2[4096];   // [64][64]
    __shared__ float sB1[64], sB2[64], sFc[64];
    __shared__ float redS[256];
    __shared__ int   redG[256];

    int t = threadIdx.x;
    for (int j = t; j < 512; j += 256)  sW1[j] = W1[j];
    for (int j = t; j < 4096; j += 256) sW2[j] = W2[j];
    if (t < 64) { sB1[t] = b1[t]; sB2[t] = b2[t]; sFc[t] = fcW[t]; }
    __syncthreads();

    int i = blockIdx.x * 256 + t;
    float s = 0.0f;
    int g = -1;
    if (i < N_NODES) {
        const float4* av = (const float4*)acc;
        float4 u0 = av[(size_t)i * 2 + 0];
        float4 u1 = av[(size_t)i * 2 + 1];
        float f[8] = {u0.x, u0.y, u0.z, u0.w, u1.x, u1.y, u1.z, u1.w};

        const float4* w1v = (const float4*)sW1;
        const float4* w2v = (const float4*)sW2;
        const float4* b1v = (const float4*)sB1;
        const float4* b2v = (const float4*)sB2;
        const float4* fcv = (const float4*)sFc;

        float h1[64];
        // layer 1: h1 = relu(f @ W1 + b1); W1[k][o] -> w1v[k*16 + o4]
        #pragma unroll
        for (int o = 0; o < 16; o++) {
            float4 a4 = b1v[o];
            #pragma unroll
            for (int k = 0; k < 8; k++) {
                float4 w = w1v[k * 16 + o];
                a4.x = fmaf(f[k], w.x, a4.x);
                a4.y = fmaf(f[k], w.y, a4.y);
                a4.z = fmaf(f[k], w.z, a4.z);
                a4.w = fmaf(f[k], w.w, a4.w);
            }
            h1[o * 4 + 0] = fmaxf(a4.x, 0.0f);
            h1[o * 4 + 1] = fmaxf(a4.y, 0.0f);
            h1[o * 4 + 2] = fmaxf(a4.z, 0.0f);
            h1[o * 4 + 3] = fmaxf(a4.w, 0.0f);
        }
        // layer 2 + head: s = relu(h1 @ W2 + b2) . fcW
        for (int o = 0; o < 16; o++) {
            float4 a4 = b2v[o];
            #pragma unroll
            for (int k = 0; k < 64; k++) {
                float4 w = w2v[k * 16 + o];
                a4.x = fmaf(h1[k], w.x, a4.x);
                a4.y = fmaf(h1[k], w.y, a4.y);
                a4.z = fmaf(h1[k], w.z, a4.z);
                a4.w = fmaf(h1[k], w.w, a4.w);
            }
            float4 fc = fcv[o];
            s += fmaxf(a4.x, 0.0f) * fc.x;
            s += fmaxf(a4.y, 0.0f) * fc.y;
            s += fmaxf(a4.z, 0.0f) * fc.z;
            s += fmaxf(a4.w, 0.0f) * fc.w;
        }
        g = batch[i];
    }

    // segmented reduction over sorted batch ids within the block
    redS[t] = s;
    redG[t] = g;
    __syncthreads();
    if (g >= 0 && (t == 0 || redG[t - 1] != g)) {
        float sum = s;
        for (int j = t + 1; j < 256 && redG[j] == g; j++) sum += redS[j];
        unsafeAtomicAdd(&out[g], sum);
    }
}

extern "C" void kernel_launch(void* const* d_in, const int* in_sizes, int n_in,
                              void* d_out, int out_size, void* d_ws, size_t ws_size,
                              hipStream_t stream) {
    const float* pos  = (const float*)d_in[0];
    const int*   z    = (const int*)  d_in[1];
    const int*   ei   = (const int*)  d_in[2];
    const int*   batch= (const int*)  d_in[3];
    const float* emb  = (const float*)d_in[4];
    const float* W1   = (const float*)d_in[5];
    const float* b1   = (const float*)d_in[6];
    const float* W2   = (const float*)d_in[7];
    const float* b2   = (const float*)d_in[8];
    const float* fcW  = (const float*)d_in[9];
    const float* fcb  = (const float*)d_in[10];
    float* out = (float*)d_out;

    float* x   = (float*)d_ws;                    // 8M floats, 32 MB
    float* acc = x + (size_t)N_NODES * 8;         // 8M floats, 32 MB

    k_features<<<(N_NODES + 255) / 256, 256, 0, stream>>>(pos, z, emb, x, acc);
    k_init_out<<<(N_GRAPHS + 255) / 256, 256, 0, stream>>>(fcb, out);
    k_scatter<<<(N_EDGES + 255) / 256, 256, 0, stream>>>(ei, x, acc);
    k_mlp_pool<<<(N_NODES + 255) / 256, 256, 0, stream>>>(acc, batch,
                                                          W1, b1, W2, b2, fcW, out);
}

// Round 2
// 4280.882 us; speedup vs baseline: 1.5724x; 1.5724x over previous
//
#include <hip/hip_runtime.h>
#include <stdint.h>

// GINNet on MI355X — R1: replace global fp32 atomic scatter (128M fabric
// atomics @ 20G/s = 6.4 ms) with bucket partition + LDS-local reduction.
//
//  k_features   : x[i] = [pos | emb(z)]                     (32 MB write)
//  k_init       : out[g] = fcb[0]; cursor[b] = 0
//  k_partition  : bucket edges by dst>>10; perm[b][j] = src<<10 | dst&1023
//                 (16M int atomics over 977 cursors + 64 MB packed writes)
//  k_bucket_red : per bucket (1024 nodes): LDS fp32 slice (stride 9, bank-
//                 conflict-free), ds_add_f32 accumulate x[src], then
//                 acc = x + slice  (coalesced)
//  k_mlp_pool   : s_i = relu(relu((x+agg)@W1+b1)@W2+b2).fcW, segmented
//                 block reduce over sorted batch -> atomicAdd(out[g])
//                 (pooled@fcW+fcb == sum_i h_i.fcW + fcb by linearity)

#define N_NODES  1000000
#define N_EDGES  16000000
#define N_GRAPHS 10000
#define NB       1024        // buckets (977 used: dst>>10, dst < 1M)
#define NBUCK    977
#define BCAP     18432       // per-bucket capacity (mean 16376, sigma 128)

__global__ __launch_bounds__(256) void k_features(
    const float* __restrict__ pos, const int* __restrict__ z,
    const float* __restrict__ emb, float* __restrict__ x)
{
    int i = blockIdx.x * 256 + threadIdx.x;
    if (i >= N_NODES) return;
    float p0 = pos[i * 3 + 0], p1 = pos[i * 3 + 1], p2 = pos[i * 3 + 2];
    const float* e = emb + z[i] * 5;
    float4* xv = (float4*)x;
    xv[(size_t)i * 2 + 0] = make_float4(p0, p1, p2, e[0]);
    xv[(size_t)i * 2 + 1] = make_float4(e[1], e[2], e[3], e[4]);
}

__global__ __launch_bounds__(256) void k_init(
    const float* __restrict__ fcb, float* __restrict__ out, int* __restrict__ cursor)
{
    int i = blockIdx.x * 256 + threadIdx.x;
    if (i < N_GRAPHS) out[i] = fcb[0];
    if (i < NB) cursor[i] = 0;
}

__global__ __launch_bounds__(256) void k_partition(
    const int* __restrict__ ei, int* __restrict__ cursor, uint32_t* __restrict__ perm)
{
    int e = blockIdx.x * 256 + threadIdx.x;
    if (e >= N_EDGES) return;
    int src = ei[e];
    int dst = ei[N_EDGES + e];
    int b = dst >> 10;
    int pos = atomicAdd(&cursor[b], 1);
    perm[(size_t)b * BCAP + pos] = ((uint32_t)src << 10) | (uint32_t)(dst & 1023);
}

__global__ __launch_bounds__(256) void k_bucket_red(
    const uint32_t* __restrict__ perm, const int* __restrict__ cursor,
    const float* __restrict__ x, float* __restrict__ acc)
{
    __shared__ float sAcc[1024 * 9];   // stride 9: banks (9*node+k)%32 uniform
    int t = threadIdx.x;
    int b = blockIdx.x;

    for (int j = t; j < 1024 * 9; j += 256) sAcc[j] = 0.0f;
    __syncthreads();

    int n = cursor[b];
    if (n > BCAP) n = BCAP;            // unreachable (36 sigma), safety only
    const uint32_t* pb = perm + (size_t)b * BCAP;
    const float4* xv = (const float4*)x;

    for (int j = t; j < n; j += 256) {
        uint32_t p = pb[j];
        uint32_t src = p >> 10;
        uint32_t low = p & 1023u;
        float4 a = xv[(size_t)src * 2 + 0];
        float4 c = xv[(size_t)src * 2 + 1];
        float* s = sAcc + low * 9;
        atomicAdd(s + 0, a.x);
        atomicAdd(s + 1, a.y);
        atomicAdd(s + 2, a.z);
        atomicAdd(s + 3, a.w);
        atomicAdd(s + 4, c.x);
        atomicAdd(s + 5, c.y);
        atomicAdd(s + 6, c.z);
        atomicAdd(s + 7, c.w);
    }
    __syncthreads();

    // acc[node] = x[node] + slice ; 1024 nodes, 4 per thread
    for (int q = t; q < 1024; q += 256) {
        int node = (b << 10) + q;
        if (node >= N_NODES) break;
        float4 a = xv[(size_t)node * 2 + 0];
        float4 c = xv[(size_t)node * 2 + 1];
        const float* s = sAcc + q * 9;
        a.x += s[0]; a.y += s[1]; a.z += s[2]; a.w += s[3];
        c.x += s[4]; c.y += s[5]; c.z += s[6]; c.w += s[7];
        float4* av = (float4*)acc;
        av[(size_t)node * 2 + 0] = a;
        av[(size_t)node * 2 + 1] = c;
    }
}

__global__ __launch_bounds__(256) void k_mlp_pool(
    const float* __restrict__ acc, const int* __restrict__ batch,
    const float* __restrict__ W1, const float* __restrict__ b1,
    const float* __restrict__ W2, const float* __restrict__ b2,
    const float* __restrict__ fcW, float* __restrict__ out)
{
    __shared__ float sW1[512];    // [8][64]
    __shared__ float sW2[4096];   // [64][64]
    __shared__ float sB1[64], sB2[64], sFc[64];
    __shared__ float redS[256];
    __shared__ int   redG[256];

    int t = threadIdx.x;
    for (int j = t; j < 512; j += 256)  sW1[j] = W1[j];
    for (int j = t; j < 4096; j += 256) sW2[j] = W2[j];
    if (t < 64) { sB1[t] = b1[t]; sB2[t] = b2[t]; sFc[t] = fcW[t]; }
    __syncthreads();

    int i = blockIdx.x * 256 + t;
    float s = 0.0f;
    int g = -1;
    if (i < N_NODES) {
        const float4* av = (const float4*)acc;
        float4 u0 = av[(size_t)i * 2 + 0];
        float4 u1 = av[(size_t)i * 2 + 1];
        float f[8] = {u0.x, u0.y, u0.z, u0.w, u1.x, u1.y, u1.z, u1.w};

        const float4* w1v = (const float4*)sW1;
        const float4* w2v = (const float4*)sW2;
        const float4* b1v = (const float4*)sB1;
        const float4* b2v = (const float4*)sB2;
        const float4* fcv = (const float4*)sFc;

        float h1[64];
        #pragma unroll
        for (int o = 0; o < 16; o++) {
            float4 a4 = b1v[o];
            #pragma unroll
            for (int k = 0; k < 8; k++) {
                float4 w = w1v[k * 16 + o];
                a4.x = fmaf(f[k], w.x, a4.x);
                a4.y = fmaf(f[k], w.y, a4.y);
                a4.z = fmaf(f[k], w.z, a4.z);
                a4.w = fmaf(f[k], w.w, a4.w);
            }
            h1[o * 4 + 0] = fmaxf(a4.x, 0.0f);
            h1[o * 4 + 1] = fmaxf(a4.y, 0.0f);
            h1[o * 4 + 2] = fmaxf(a4.z, 0.0f);
            h1[o * 4 + 3] = fmaxf(a4.w, 0.0f);
        }
        for (int o = 0; o < 16; o++) {
            float4 a4 = b2v[o];
            #pragma unroll
            for (int k = 0; k < 64; k++) {
                float4 w = w2v[k * 16 + o];
                a4.x = fmaf(h1[k], w.x, a4.x);
                a4.y = fmaf(h1[k], w.y, a4.y);
                a4.z = fmaf(h1[k], w.z, a4.z);
                a4.w = fmaf(h1[k], w.w, a4.w);
            }
            float4 fc = fcv[o];
            s += fmaxf(a4.x, 0.0f) * fc.x;
            s += fmaxf(a4.y, 0.0f) * fc.y;
            s += fmaxf(a4.z, 0.0f) * fc.z;
            s += fmaxf(a4.w, 0.0f) * fc.w;
        }
        g = batch[i];
    }

    redS[t] = s;
    redG[t] = g;
    __syncthreads();
    if (g >= 0 && (t == 0 || redG[t - 1] != g)) {
        float sum = s;
        for (int j = t + 1; j < 256 && redG[j] == g; j++) sum += redS[j];
        unsafeAtomicAdd(&out[g], sum);
    }
}

extern "C" void kernel_launch(void* const* d_in, const int* in_sizes, int n_in,
                              void* d_out, int out_size, void* d_ws, size_t ws_size,
                              hipStream_t stream) {
    const float* pos  = (const float*)d_in[0];
    const int*   z    = (const int*)  d_in[1];
    const int*   ei   = (const int*)  d_in[2];
    const int*   batch= (const int*)  d_in[3];
    const float* emb  = (const float*)d_in[4];
    const float* W1   = (const float*)d_in[5];
    const float* b1   = (const float*)d_in[6];
    const float* W2   = (const float*)d_in[7];
    const float* b2   = (const float*)d_in[8];
    const float* fcW  = (const float*)d_in[9];
    const float* fcb  = (const float*)d_in[10];
    float* out = (float*)d_out;

    // workspace layout (all 16B-aligned offsets)
    float*    x      = (float*)d_ws;                               // 32,000,000 B
    uint32_t* perm   = (uint32_t*)(x + (size_t)N_NODES * 8);       // 75,497,472 B
    int*      cursor = (int*)(perm + (size_t)NB * BCAP);           //      4,096 B
    float*    acc    = (float*)(cursor + NB);                      // 32,000,000 B

    k_features <<<(N_NODES + 255) / 256, 256, 0, stream>>>(pos, z, emb, x);
    k_init     <<<(N_GRAPHS + 255) / 256, 256, 0, stream>>>(fcb, out, cursor);
    k_partition<<<(N_EDGES + 255) / 256, 256, 0, stream>>>(ei, cursor, perm);
    k_bucket_red<<<NBUCK, 256, 0, stream>>>(perm, cursor, x, acc);
    k_mlp_pool <<<(N_NODES + 255) / 256, 256, 0, stream>>>(acc, batch,
                                                           W1, b1, W2, b2, fcW, out);
}

// Round 3
// 1185.244 us; speedup vs baseline: 5.6793x; 3.6118x over previous
//
#include <hip/hip_runtime.h>
#include <stdint.h>

// GINNet on MI355X — R2: k_partition rewritten as block-local counting sort.
// R1's per-edge global atomic (16M returning atomics on 977 addresses, each
// gating a scattered 4B write -> 44B txn) was the 3.2 ms bottleneck.
//
//  k_features   : x[i] = [pos | emb(z)]
//  k_init       : out[g] = fcb[0]; cursor[b] = 0
//  k_partition  : per block of 16384 edges: LDS histogram -> 1 global atomic
//                 per (block,bucket) reservation -> LDS counting sort ->
//                 coalesced run writes (mean 64B) of packed src<<10|dst&1023
//  k_bucket_red : per bucket (1024 nodes): LDS fp32 slice (stride 9),
//                 ds_add_f32 accumulate x[src], then acc = x + slice
//  k_mlp_pool   : s_i = relu(relu((x+agg)@W1+b1)@W2+b2).fcW, segmented
//                 block reduce over sorted batch -> atomicAdd(out[g])

#define N_NODES  1000000
#define N_EDGES  16000000
#define N_GRAPHS 10000
#define NB       1024        // buckets = dst>>10 (977 used)
#define NBUCK    977
#define BCAP     18432       // per-bucket capacity (mean 16376, sigma ~128)
#define EPB      16384       // edges per partition block
#define PBLK     977         // ceil(16e6 / 16384)

__global__ __launch_bounds__(256) void k_features(
    const float* __restrict__ pos, const int* __restrict__ z,
    const float* __restrict__ emb, float* __restrict__ x)
{
    int i = blockIdx.x * 256 + threadIdx.x;
    if (i >= N_NODES) return;
    float p0 = pos[i * 3 + 0], p1 = pos[i * 3 + 1], p2 = pos[i * 3 + 2];
    const float* e = emb + z[i] * 5;
    float4* xv = (float4*)x;
    xv[(size_t)i * 2 + 0] = make_float4(p0, p1, p2, e[0]);
    xv[(size_t)i * 2 + 1] = make_float4(e[1], e[2], e[3], e[4]);
}

__global__ __launch_bounds__(256) void k_init(
    const float* __restrict__ fcb, float* __restrict__ out, int* __restrict__ cursor)
{
    int i = blockIdx.x * 256 + threadIdx.x;
    if (i < N_GRAPHS) out[i] = fcb[0];
    if (i < NB) cursor[i] = 0;
}

__global__ __launch_bounds__(256) void k_partition(
    const int* __restrict__ ei, int* __restrict__ cursor, uint32_t* __restrict__ perm)
{
    __shared__ uint32_t sVal[EPB];   // 64 KB: bucket-sorted packed edges
    __shared__ int sHist[NB];        // counts -> exclusive prefix (lstart)
    __shared__ int sGB[NB];          // global base per bucket
    __shared__ int sCur[NB];         // scatter cursor
    __shared__ int sScan[256];

    int t = threadIdx.x;
    int e0 = blockIdx.x * EPB;
    int nE = N_EDGES - e0; if (nE > EPB) nE = EPB;

    for (int c = t; c < NB; c += 256) sHist[c] = 0;
    __syncthreads();

    const int4* src4 = (const int4*)ei;
    const int4* dst4 = (const int4*)(ei + N_EDGES);
    int i40 = e0 >> 2;

    // Phase A: histogram of dst buckets (LDS atomics)
    #pragma unroll
    for (int jj = 0; jj < EPB / 1024; jj++) {
        int i4 = i40 + jj * 256 + t;
        if (i4 * 4 < N_EDGES) {
            int4 d = dst4[i4];
            atomicAdd(&sHist[d.x >> 10], 1);
            atomicAdd(&sHist[d.y >> 10], 1);
            atomicAdd(&sHist[d.z >> 10], 1);
            atomicAdd(&sHist[d.w >> 10], 1);
        }
    }
    __syncthreads();

    // Phase B1: reserve global space (<=1024 atomics per block, not per edge)
    #pragma unroll
    for (int k = 0; k < 4; k++) {
        int c = t * 4 + k;
        int cnt = sHist[c];
        sGB[c] = cnt ? atomicAdd(&cursor[c], cnt) : 0;
    }
    // Phase B2: exclusive prefix of sHist (two-level scan)
    int pt = 0;
    #pragma unroll
    for (int k = 0; k < 4; k++) pt += sHist[t * 4 + k];
    sScan[t] = pt;
    __syncthreads();
    for (int off = 1; off < 256; off <<= 1) {
        int v = (t >= off) ? sScan[t - off] : 0;
        __syncthreads();
        sScan[t] += v;
        __syncthreads();
    }
    int base = (t == 0) ? 0 : sScan[t - 1];
    #pragma unroll
    for (int k = 0; k < 4; k++) {
        int c = t * 4 + k;
        int cnt = sHist[c];
        sHist[c] = base;      // lstart (exclusive prefix)
        sCur[c]  = base;      // running scatter cursor
        base += cnt;
    }
    __syncthreads();

    // Phase C: counting-sort scatter into LDS (returning LDS atomics only)
    #pragma unroll
    for (int jj = 0; jj < EPB / 1024; jj++) {
        int i4 = i40 + jj * 256 + t;
        if (i4 * 4 < N_EDGES) {
            int4 s = src4[i4];
            int4 d = dst4[i4];
            int b, p;
            b = d.x >> 10; p = atomicAdd(&sCur[b], 1);
            sVal[p] = ((uint32_t)s.x << 10) | (uint32_t)(d.x & 1023);
            b = d.y >> 10; p = atomicAdd(&sCur[b], 1);
            sVal[p] = ((uint32_t)s.y << 10) | (uint32_t)(d.y & 1023);
            b = d.z >> 10; p = atomicAdd(&sCur[b], 1);
            sVal[p] = ((uint32_t)s.z << 10) | (uint32_t)(d.z & 1023);
            b = d.w >> 10; p = atomicAdd(&sCur[b], 1);
            sVal[p] = ((uint32_t)s.w << 10) | (uint32_t)(d.w & 1023);
        }
    }
    __syncthreads();

    // Phase D: coalesced run writes; bucket-of-j via binary search on lstart
    for (int j = t; j < nE; j += 256) {
        uint32_t v = sVal[j];
        int lo = 0;
        #pragma unroll
        for (int st = 512; st; st >>= 1) {
            int cand = lo + st;
            if (cand < NB && sHist[cand] <= j) lo = cand;
        }
        int off = j - sHist[lo];
        perm[(size_t)lo * BCAP + sGB[lo] + off] = v;
    }
}

__global__ __launch_bounds__(256) void k_bucket_red(
    const uint32_t* __restrict__ perm, const int* __restrict__ cursor,
    const float* __restrict__ x, float* __restrict__ acc)
{
    __shared__ float sAcc[1024 * 9];   // stride 9: banks (9*node+k)%32 uniform
    int t = threadIdx.x;
    int b = blockIdx.x;

    for (int j = t; j < 1024 * 9; j += 256) sAcc[j] = 0.0f;
    __syncthreads();

    int n = cursor[b];
    if (n > BCAP) n = BCAP;            // unreachable (36 sigma), safety only
    const uint32_t* pb = perm + (size_t)b * BCAP;
    const float4* xv = (const float4*)x;

    for (int j = t; j < n; j += 256) {
        uint32_t p = pb[j];
        uint32_t src = p >> 10;
        uint32_t low = p & 1023u;
        float4 a = xv[(size_t)src * 2 + 0];
        float4 c = xv[(size_t)src * 2 + 1];
        float* s = sAcc + low * 9;
        atomicAdd(s + 0, a.x);
        atomicAdd(s + 1, a.y);
        atomicAdd(s + 2, a.z);
        atomicAdd(s + 3, a.w);
        atomicAdd(s + 4, c.x);
        atomicAdd(s + 5, c.y);
        atomicAdd(s + 6, c.z);
        atomicAdd(s + 7, c.w);
    }
    __syncthreads();

    for (int q = t; q < 1024; q += 256) {
        int node = (b << 10) + q;
        if (node >= N_NODES) break;
        float4 a = xv[(size_t)node * 2 + 0];
        float4 c = xv[(size_t)node * 2 + 1];
        const float* s = sAcc + q * 9;
        a.x += s[0]; a.y += s[1]; a.z += s[2]; a.w += s[3];
        c.x += s[4]; c.y += s[5]; c.z += s[6]; c.w += s[7];
        float4* av = (float4*)acc;
        av[(size_t)node * 2 + 0] = a;
        av[(size_t)node * 2 + 1] = c;
    }
}

__global__ __launch_bounds__(256) void k_mlp_pool(
    const float* __restrict__ acc, const int* __restrict__ batch,
    const float* __restrict__ W1, const float* __restrict__ b1,
    const float* __restrict__ W2, const float* __restrict__ b2,
    const float* __restrict__ fcW, float* __restrict__ out)
{
    __shared__ float sW1[512];    // [8][64]
    __shared__ float sW2[4096];   // [64][64]
    __shared__ float sB1[64], sB2[64], sFc[64];
    __shared__ float redS[256];
    __shared__ int   redG[256];

    int t = threadIdx.x;
    for (int j = t; j < 512; j += 256)  sW1[j] = W1[j];
    for (int j = t; j < 4096; j += 256) sW2[j] = W2[j];
    if (t < 64) { sB1[t] = b1[t]; sB2[t] = b2[t]; sFc[t] = fcW[t]; }
    __syncthreads();

    int i = blockIdx.x * 256 + t;
    float s = 0.0f;
    int g = -1;
    if (i < N_NODES) {
        const float4* av = (const float4*)acc;
        float4 u0 = av[(size_t)i * 2 + 0];
        float4 u1 = av[(size_t)i * 2 + 1];
        float f[8] = {u0.x, u0.y, u0.z, u0.w, u1.x, u1.y, u1.z, u1.w};

        const float4* w1v = (const float4*)sW1;
        const float4* w2v = (const float4*)sW2;
        const float4* b1v = (const float4*)sB1;
        const float4* b2v = (const float4*)sB2;
        const float4* fcv = (const float4*)sFc;

        float h1[64];
        #pragma unroll
        for (int o = 0; o < 16; o++) {
            float4 a4 = b1v[o];
            #pragma unroll
            for (int k = 0; k < 8; k++) {
                float4 w = w1v[k * 16 + o];
                a4.x = fmaf(f[k], w.x, a4.x);
                a4.y = fmaf(f[k], w.y, a4.y);
                a4.z = fmaf(f[k], w.z, a4.z);
                a4.w = fmaf(f[k], w.w, a4.w);
            }
            h1[o * 4 + 0] = fmaxf(a4.x, 0.0f);
            h1[o * 4 + 1] = fmaxf(a4.y, 0.0f);
            h1[o * 4 + 2] = fmaxf(a4.z, 0.0f);
            h1[o * 4 + 3] = fmaxf(a4.w, 0.0f);
        }
        for (int o = 0; o < 16; o++) {
            float4 a4 = b2v[o];
            #pragma unroll
            for (int k = 0; k < 64; k++) {
                float4 w = w2v[k * 16 + o];
                a4.x = fmaf(h1[k], w.x, a4.x);
                a4.y = fmaf(h1[k], w.y, a4.y);
                a4.z = fmaf(h1[k], w.z, a4.z);
                a4.w = fmaf(h1[k], w.w, a4.w);
            }
            float4 fc = fcv[o];
            s += fmaxf(a4.x, 0.0f) * fc.x;
            s += fmaxf(a4.y, 0.0f) * fc.y;
            s += fmaxf(a4.z, 0.0f) * fc.z;
            s += fmaxf(a4.w, 0.0f) * fc.w;
        }
        g = batch[i];
    }

    redS[t] = s;
    redG[t] = g;
    __syncthreads();
    if (g >= 0 && (t == 0 || redG[t - 1] != g)) {
        float sum = s;
        for (int j = t + 1; j < 256 && redG[j] == g; j++) sum += redS[j];
        unsafeAtomicAdd(&out[g], sum);
    }
}

extern "C" void kernel_launch(void* const* d_in, const int* in_sizes, int n_in,
                              void* d_out, int out_size, void* d_ws, size_t ws_size,
                              hipStream_t stream) {
    const float* pos  = (const float*)d_in[0];
    const int*   z    = (const int*)  d_in[1];
    const int*   ei   = (const int*)  d_in[2];
    const int*   batch= (const int*)  d_in[3];
    const float* emb  = (const float*)d_in[4];
    const float* W1   = (const float*)d_in[5];
    const float* b1   = (const float*)d_in[6];
    const float* W2   = (const float*)d_in[7];
    const float* b2   = (const float*)d_in[8];
    const float* fcW  = (const float*)d_in[9];
    const float* fcb  = (const float*)d_in[10];
    float* out = (float*)d_out;

    float*    x      = (float*)d_ws;                               // 32,000,000 B
    uint32_t* perm   = (uint32_t*)(x + (size_t)N_NODES * 8);       // 75,497,472 B
    int*      cursor = (int*)(perm + (size_t)NB * BCAP);           //      4,096 B
    float*    acc    = (float*)(cursor + NB);                      // 32,000,000 B

    k_features <<<(N_NODES + 255) / 256, 256, 0, stream>>>(pos, z, emb, x);
    k_init     <<<(N_GRAPHS + 255) / 256, 256, 0, stream>>>(fcb, out, cursor);
    k_partition<<<PBLK, 256, 0, stream>>>(ei, cursor, perm);
    k_bucket_red<<<NBUCK, 256, 0, stream>>>(perm, cursor, x, acc);
    k_mlp_pool <<<(N_NODES + 255) / 256, 256, 0, stream>>>(acc, batch,
                                                           W1, b1, W2, b2, fcW, out);
}

// Round 4
// 850.153 us; speedup vs baseline: 7.9178x; 1.3942x over previous
//
#include <hip/hip_runtime.h>
#include <stdint.h>

// GINNet on MI355X — R3: bucket_red was latency-bound (VALUBusy 0.6%, occ 29%,
// 57 B HBM per random 32 B gather). Changes:
//  * gather px[i]={pos,z} (16 B, ONE load) instead of x[i] (32 B, two loads);
//    LDS slice holds 3 pos sums + 5 one-hot z counts; emb aggregate = cnt@emb
//    reconstructed at writeout (emb has only 5 rows).
//  * 2 blocks per bucket split by dst bit 9 -> 512-node slice = 18.4 KB LDS
//    -> 8 blocks/CU (32 waves) and 1954 blocks for latency hiding.
// Partition kernel byte-identical to R2 (proven).
//
//  k_features   : px[i] = {pos | bitcast(z)}
//  k_init       : out[g] = fcb[0]; cursor[b] = 0
//  k_partition  : block-local counting sort of edges by dst>>10 into perm
//  k_bucket_red : per (bucket, half): LDS {pos-sum,z-count} slice, then
//                 acc = [pos+possum | emb[z]+cnt@emb]
//  k_mlp_pool   : s_i = relu(relu(acc@W1+b1)@W2+b2).fcW, segmented block
//                 reduce over sorted batch -> atomicAdd(out[g])

#define N_NODES  1000000
#define N_EDGES  16000000
#define N_GRAPHS 10000
#define NB       1024        // buckets = dst>>10 (977 used)
#define NBUCK    977
#define BCAP     18432       // per-bucket capacity (mean 16376, sigma ~128)
#define EPB      16384       // edges per partition block
#define PBLK     977         // ceil(16e6 / 16384)

__global__ __launch_bounds__(256) void k_features(
    const float* __restrict__ pos, const int* __restrict__ z,
    float4* __restrict__ px)
{
    int i = blockIdx.x * 256 + threadIdx.x;
    if (i >= N_NODES) return;
    px[i] = make_float4(pos[i * 3 + 0], pos[i * 3 + 1], pos[i * 3 + 2],
                        __int_as_float(z[i]));
}

__global__ __launch_bounds__(256) void k_init(
    const float* __restrict__ fcb, float* __restrict__ out, int* __restrict__ cursor)
{
    int i = blockIdx.x * 256 + threadIdx.x;
    if (i < N_GRAPHS) out[i] = fcb[0];
    if (i < NB) cursor[i] = 0;
}

__global__ __launch_bounds__(256) void k_partition(
    const int* __restrict__ ei, int* __restrict__ cursor, uint32_t* __restrict__ perm)
{
    __shared__ uint32_t sVal[EPB];   // 64 KB: bucket-sorted packed edges
    __shared__ int sHist[NB];        // counts -> exclusive prefix (lstart)
    __shared__ int sGB[NB];          // global base per bucket
    __shared__ int sCur[NB];         // scatter cursor
    __shared__ int sScan[256];

    int t = threadIdx.x;
    int e0 = blockIdx.x * EPB;
    int nE = N_EDGES - e0; if (nE > EPB) nE = EPB;

    for (int c = t; c < NB; c += 256) sHist[c] = 0;
    __syncthreads();

    const int4* src4 = (const int4*)ei;
    const int4* dst4 = (const int4*)(ei + N_EDGES);
    int i40 = e0 >> 2;

    // Phase A: histogram of dst buckets (LDS atomics)
    #pragma unroll
    for (int jj = 0; jj < EPB / 1024; jj++) {
        int i4 = i40 + jj * 256 + t;
        if (i4 * 4 < N_EDGES) {
            int4 d = dst4[i4];
            atomicAdd(&sHist[d.x >> 10], 1);
            atomicAdd(&sHist[d.y >> 10], 1);
            atomicAdd(&sHist[d.z >> 10], 1);
            atomicAdd(&sHist[d.w >> 10], 1);
        }
    }
    __syncthreads();

    // Phase B1: reserve global space (<=1024 atomics per block, not per edge)
    #pragma unroll
    for (int k = 0; k < 4; k++) {
        int c = t * 4 + k;
        int cnt = sHist[c];
        sGB[c] = cnt ? atomicAdd(&cursor[c], cnt) : 0;
    }
    // Phase B2: exclusive prefix of sHist (two-level scan)
    int pt = 0;
    #pragma unroll
    for (int k = 0; k < 4; k++) pt += sHist[t * 4 + k];
    sScan[t] = pt;
    __syncthreads();
    for (int off = 1; off < 256; off <<= 1) {
        int v = (t >= off) ? sScan[t - off] : 0;
        __syncthreads();
        sScan[t] += v;
        __syncthreads();
    }
    int base = (t == 0) ? 0 : sScan[t - 1];
    #pragma unroll
    for (int k = 0; k < 4; k++) {
        int c = t * 4 + k;
        int cnt = sHist[c];
        sHist[c] = base;      // lstart (exclusive prefix)
        sCur[c]  = base;      // running scatter cursor
        base += cnt;
    }
    __syncthreads();

    // Phase C: counting-sort scatter into LDS (returning LDS atomics only)
    #pragma unroll
    for (int jj = 0; jj < EPB / 1024; jj++) {
        int i4 = i40 + jj * 256 + t;
        if (i4 * 4 < N_EDGES) {
            int4 s = src4[i4];
            int4 d = dst4[i4];
            int b, p;
            b = d.x >> 10; p = atomicAdd(&sCur[b], 1);
            sVal[p] = ((uint32_t)s.x << 10) | (uint32_t)(d.x & 1023);
            b = d.y >> 10; p = atomicAdd(&sCur[b], 1);
            sVal[p] = ((uint32_t)s.y << 10) | (uint32_t)(d.y & 1023);
            b = d.z >> 10; p = atomicAdd(&sCur[b], 1);
            sVal[p] = ((uint32_t)s.z << 10) | (uint32_t)(d.z & 1023);
            b = d.w >> 10; p = atomicAdd(&sCur[b], 1);
            sVal[p] = ((uint32_t)s.w << 10) | (uint32_t)(d.w & 1023);
        }
    }
    __syncthreads();

    // Phase D: coalesced run writes; bucket-of-j via binary search on lstart
    for (int j = t; j < nE; j += 256) {
        uint32_t v = sVal[j];
        int lo = 0;
        #pragma unroll
        for (int st = 512; st; st >>= 1) {
            int cand = lo + st;
            if (cand < NB && sHist[cand] <= j) lo = cand;
        }
        int off = j - sHist[lo];
        perm[(size_t)lo * BCAP + sGB[lo] + off] = v;
    }
}

__global__ __launch_bounds__(256) void k_bucket_red(
    const uint32_t* __restrict__ perm, const int* __restrict__ cursor,
    const float4* __restrict__ px, const float* __restrict__ emb,
    float* __restrict__ acc)
{
    __shared__ float sAcc[512 * 9];   // 18.4 KB: 3 pos sums + 5 z counts, stride 9
    __shared__ float sEmb[25];
    int t = threadIdx.x;
    int r = blockIdx.x;
    int b = r >> 1;          // bucket
    int h = r & 1;           // dst bit 9 half

    for (int j = t; j < 512 * 9; j += 256) sAcc[j] = 0.0f;
    if (t < 25) sEmb[t] = emb[t];
    __syncthreads();

    int n = cursor[b];
    if (n > BCAP) n = BCAP;            // unreachable (~17 sigma), safety only
    const uint32_t* pb = perm + (size_t)b * BCAP;

    #pragma unroll 2
    for (int j = t; j < n; j += 256) {
        uint32_t p = pb[j];
        if ((int)((p >> 9) & 1u) != h) continue;
        float4 g = px[p >> 10];
        float* s = sAcc + (p & 511u) * 9;
        atomicAdd(s + 0, g.x);
        atomicAdd(s + 1, g.y);
        atomicAdd(s + 2, g.z);
        atomicAdd(s + 3 + __float_as_int(g.w), 1.0f);
    }
    __syncthreads();

    // writeout: acc[node] = [pos + possum | emb[z] + cnt @ emb]
    for (int q = t; q < 512; q += 256) {
        int node = (b << 10) + (h << 9) + q;
        if (node >= N_NODES) break;
        float4 me = px[node];
        int mz = __float_as_int(me.w);
        const float* s = sAcc + q * 9;
        float c0 = s[3], c1 = s[4], c2 = s[5], c3 = s[6], c4 = s[7];
        float e[5];
        #pragma unroll
        for (int c = 0; c < 5; c++) {
            e[c] = sEmb[mz * 5 + c]
                 + c0 * sEmb[0 * 5 + c] + c1 * sEmb[1 * 5 + c]
                 + c2 * sEmb[2 * 5 + c] + c3 * sEmb[3 * 5 + c]
                 + c4 * sEmb[4 * 5 + c];
        }
        float4* av = (float4*)acc;
        av[(size_t)node * 2 + 0] = make_float4(me.x + s[0], me.y + s[1],
                                               me.z + s[2], e[0]);
        av[(size_t)node * 2 + 1] = make_float4(e[1], e[2], e[3], e[4]);
    }
}

__global__ __launch_bounds__(256) void k_mlp_pool(
    const float* __restrict__ acc, const int* __restrict__ batch,
    const float* __restrict__ W1, const float* __restrict__ b1,
    const float* __restrict__ W2, const float* __restrict__ b2,
    const float* __restrict__ fcW, float* __restrict__ out)
{
    __shared__ float sW1[512];    // [8][64]
    __shared__ float sW2[4096];   // [64][64]
    __shared__ float sB1[64], sB2[64], sFc[64];
    __shared__ float redS[256];
    __shared__ int   redG[256];

    int t = threadIdx.x;
    for (int j = t; j < 512; j += 256)  sW1[j] = W1[j];
    for (int j = t; j < 4096; j += 256) sW2[j] = W2[j];
    if (t < 64) { sB1[t] = b1[t]; sB2[t] = b2[t]; sFc[t] = fcW[t]; }
    __syncthreads();

    int i = blockIdx.x * 256 + t;
    float s = 0.0f;
    int g = -1;
    if (i < N_NODES) {
        const float4* av = (const float4*)acc;
        float4 u0 = av[(size_t)i * 2 + 0];
        float4 u1 = av[(size_t)i * 2 + 1];
        float f[8] = {u0.x, u0.y, u0.z, u0.w, u1.x, u1.y, u1.z, u1.w};

        const float4* w1v = (const float4*)sW1;
        const float4* w2v = (const float4*)sW2;
        const float4* b1v = (const float4*)sB1;
        const float4* b2v = (const float4*)sB2;
        const float4* fcv = (const float4*)sFc;

        float h1[64];
        #pragma unroll
        for (int o = 0; o < 16; o++) {
            float4 a4 = b1v[o];
            #pragma unroll
            for (int k = 0; k < 8; k++) {
                float4 w = w1v[k * 16 + o];
                a4.x = fmaf(f[k], w.x, a4.x);
                a4.y = fmaf(f[k], w.y, a4.y);
                a4.z = fmaf(f[k], w.z, a4.z);
                a4.w = fmaf(f[k], w.w, a4.w);
            }
            h1[o * 4 + 0] = fmaxf(a4.x, 0.0f);
            h1[o * 4 + 1] = fmaxf(a4.y, 0.0f);
            h1[o * 4 + 2] = fmaxf(a4.z, 0.0f);
            h1[o * 4 + 3] = fmaxf(a4.w, 0.0f);
        }
        for (int o = 0; o < 16; o++) {
            float4 a4 = b2v[o];
            #pragma unroll
            for (int k = 0; k < 64; k++) {
                float4 w = w2v[k * 16 + o];
                a4.x = fmaf(h1[k], w.x, a4.x);
                a4.y = fmaf(h1[k], w.y, a4.y);
                a4.z = fmaf(h1[k], w.z, a4.z);
                a4.w = fmaf(h1[k], w.w, a4.w);
            }
            float4 fc = fcv[o];
            s += fmaxf(a4.x, 0.0f) * fc.x;
            s += fmaxf(a4.y, 0.0f) * fc.y;
            s += fmaxf(a4.z, 0.0f) * fc.z;
            s += fmaxf(a4.w, 0.0f) * fc.w;
        }
        g = batch[i];
    }

    redS[t] = s;
    redG[t] = g;
    __syncthreads();
    if (g >= 0 && (t == 0 || redG[t - 1] != g)) {
        float sum = s;
        for (int j = t + 1; j < 256 && redG[j] == g; j++) sum += redS[j];
        unsafeAtomicAdd(&out[g], sum);
    }
}

extern "C" void kernel_launch(void* const* d_in, const int* in_sizes, int n_in,
                              void* d_out, int out_size, void* d_ws, size_t ws_size,
                              hipStream_t stream) {
    const float* pos  = (const float*)d_in[0];
    const int*   z    = (const int*)  d_in[1];
    const int*   ei   = (const int*)  d_in[2];
    const int*   batch= (const int*)  d_in[3];
    const float* emb  = (const float*)d_in[4];
    const float* W1   = (const float*)d_in[5];
    const float* b1   = (const float*)d_in[6];
    const float* W2   = (const float*)d_in[7];
    const float* b2   = (const float*)d_in[8];
    const float* fcW  = (const float*)d_in[9];
    const float* fcb  = (const float*)d_in[10];
    float* out = (float*)d_out;

    // workspace layout (16B-aligned): px 16 MB | perm 75.5 MB | cursor | acc 32 MB
    float4*   px     = (float4*)d_ws;
    uint32_t* perm   = (uint32_t*)((float*)d_ws + (size_t)N_NODES * 4);
    int*      cursor = (int*)(perm + (size_t)NB * BCAP);
    float*    acc    = (float*)(cursor + NB);

    k_features <<<(N_NODES + 255) / 256, 256, 0, stream>>>(pos, z, px);
    k_init     <<<(N_GRAPHS + 255) / 256, 256, 0, stream>>>(fcb, out, cursor);
    k_partition<<<PBLK, 256, 0, stream>>>(ei, cursor, perm);
    k_bucket_red<<<NBUCK * 2, 256, 0, stream>>>(perm, cursor, px, emb, acc);
    k_mlp_pool <<<(N_NODES + 255) / 256, 256, 0, stream>>>(acc, batch,
                                                           W1, b1, W2, b2, fcW, out);
}